// Round 8
// baseline (245.368 us; speedup 1.0000x reference)
//
#include <hip/hip_runtime.h>
#include <math.h>

// ---- geometry ----
// Grid 50^3, coords shifted +1 -> occupy [1,50]. Dense key = (z*54+y)*64+x.
#define GY 54
#define NROWS (54*54*64)      // 186624 keys

// brick 8x4x4 = 128 output voxels per block; halo 10x6x6 = 360 rows
#define HX 10
#define HY 6
#define HXY 60
#define NH 360
#define NBX 7                 // ceil(50/8)
#define NBY 13
#define NBRICK (7*13*13)      // 1183
#define SLAB 148              // ceil(1183/8) bricks per XCD

#define LDK 72                // LDS row stride in bf16 (144 B = 9*16B)

typedef __bf16  bf16x8 __attribute__((ext_vector_type(8)));
typedef float  f32x16 __attribute__((ext_vector_type(16)));

// ---- fused prep: maps + reverse keys + W -> Wt (bf16, [27][cout][cin]) ----
// No memset needed: conv validates every map entry against ikey/okey.
__global__ void prep_kernel(const float* __restrict__ ipos, int n,
                            const float* __restrict__ opos, int m,
                            const float* __restrict__ vsp,
                            const float* __restrict__ W,
                            int* __restrict__ imap, int* __restrict__ ikey,
                            int* __restrict__ omap, int* __restrict__ okey,
                            __bf16* __restrict__ Wt) {
    int i = blockIdx.x * 256 + threadIdx.x;
    float vs = vsp[0];
    if (i < n) {
        int x = (int)floorf(ipos[3*i+0] / vs) + 1;
        int y = (int)floorf(ipos[3*i+1] / vs) + 1;
        int z = (int)floorf(ipos[3*i+2] / vs) + 1;
        int key = (z * GY + y) * 64 + x;
        ikey[i] = key;
        imap[key] = i;
    } else if (i < n + m) {
        int j = i - n;
        int x = (int)floorf(opos[3*j+0] / vs) + 1;
        int y = (int)floorf(opos[3*j+1] / vs) + 1;
        int z = (int)floorf(opos[3*j+2] / vs) + 1;
        int key = (z * GY + y) * 64 + x;
        okey[j] = key;
        omap[key] = j;
    } else if (i < n + m + 27*64*64) {
        int k  = i - n - m;
        int t  = k >> 12;
        int r  = k & 4095;
        int ci = r >> 6;
        int co = r & 63;
        Wt[(t << 12) + (co << 6) + ci] = (__bf16)W[k];
    }
}

__global__ __launch_bounds__(256, 2) void conv_kernel(
    const float* __restrict__ feats,    // [N,64] fp32
    const __bf16* __restrict__ Wt,      // [27][64cout][64cin]
    const float* __restrict__ bias,     // [64]
    const int*   __restrict__ imap,
    const int*   __restrict__ ikey,
    const int*   __restrict__ omap,
    const int*   __restrict__ okey,
    float*       __restrict__ out,      // [M,64]
    int N, int M)
{
    __shared__ __align__(16) __bf16 halo[NH * LDK];    // 51840 B
    __shared__ int obuf[128];                          //   512 B
    // total LDS 52.4 KB -> up to 3 blocks/CU if VGPR allows

    const int tid = threadIdx.x;

    // XCD slab swizzle
    int q = (blockIdx.x & 7) * SLAB + (blockIdx.x >> 3);
    if (q >= NBRICK) return;   // block-uniform exit (before any barrier)
    const int bx = q % NBX;
    int rem = q / NBX;
    const int by = rem % NBY;
    const int bz = rem / NBY;

    // compute roles: wave = z-slice (1 m-tile), both n-tiles (all 64 couts)
    const int wave  = tid >> 6;
    const int lane  = tid & 63;
    const int lrow  = lane & 31;
    const int halfk = lane >> 5;

    // ---- B register pipeline: issue taps 0 and 1 NOW (overlap halo fill) ----
    const __bf16* Wl = Wt + lrow * 64 + halfk * 8;   // [cout=lrow (+32)], k-offset
    bf16x8 Bp0[8], Bp1[8];   // [nt*4 + kc] for taps (t even)/(t odd) phases
    #pragma unroll
    for (int kc = 0; kc < 4; ++kc) {
        Bp0[kc]     = *(const bf16x8*)(Wl + kc * 16);
        Bp0[4 + kc] = *(const bf16x8*)(Wl + 2048 + kc * 16);
        Bp1[kc]     = *(const bf16x8*)(Wl + 4096 + kc * 16);
        Bp1[4 + kc] = *(const bf16x8*)(Wl + 4096 + 2048 + kc * 16);
    }

    // ---- halo fill: gather fp32 rows via validated imap, convert to bf16 ----
    #pragma unroll
    for (int it = 0; it < 12; ++it) {
        int task = it * 256 + tid;
        if (task < NH * 8) {
            int r = task >> 3, c = task & 7;
            int xs = r % HX;
            int t2 = r / HX;
            int ys = t2 % HY;
            int zs = t2 / HY;
            int key = ((bz*4 + zs) * GY + (by*4 + ys)) * 64 + (bx*8 + xs);
            int idx = imap[key];
            int cl  = min(max(idx, 0), N - 1);
            bool ok = (idx >= 0 && idx < N && ikey[cl] == key);
            bf16x8 v;
            if (ok) {
                const float4* s = (const float4*)(feats + (size_t)idx * 64 + c * 8);
                float4 f0 = s[0], f1 = s[1];
                v[0]=(__bf16)f0.x; v[1]=(__bf16)f0.y; v[2]=(__bf16)f0.z; v[3]=(__bf16)f0.w;
                v[4]=(__bf16)f1.x; v[5]=(__bf16)f1.y; v[6]=(__bf16)f1.z; v[7]=(__bf16)f1.w;
            } else {
                #pragma unroll
                for (int j = 0; j < 8; ++j) v[j] = (__bf16)0.f;
            }
            *(bf16x8*)(halo + r * LDK + c * 8) = v;
        }
    }
    // ---- output-row indices (validated) ----
    if (tid < 128) {
        int x = tid & 7, y = (tid >> 3) & 3, z = tid >> 5;
        int key = ((bz*4 + z + 1) * GY + (by*4 + y + 1)) * 64 + (bx*8 + x + 1);
        int o = omap[key];
        int cl = min(max(o, 0), M - 1);
        obuf[tid] = (o >= 0 && o < M && okey[cl] == key) ? o : -1;
    }

    const int xv = lrow & 7, yv = (lrow >> 3) & 3;
    const __bf16* Abase = halo + ((wave + 1) * HXY + (yv + 1) * HX + (xv + 1)) * LDK
                               + halfk * 8;

    f32x16 acc0, acc1;
    #pragma unroll
    for (int i = 0; i < 16; ++i) { acc0[i] = 0.f; acc1[i] = 0.f; }

    __syncthreads();   // the ONLY barrier: halo + obuf visible; halo static after

    // ---- A register pipeline: taps 0 and 1 from LDS ----
    bf16x8 Ap0[4], Ap1[4];
    {
        const __bf16* a0 = Abase + (-1 * HXY - 1 * HX - 1) * LDK;  // tap0 d=(-1,-1,-1)
        const __bf16* a1 = Abase + (-1 * HXY - 1 * HX + 0) * LDK;  // tap1 d=( 0,-1,-1)
        #pragma unroll
        for (int kc = 0; kc < 4; ++kc) {
            Ap0[kc] = *(const bf16x8*)(a0 + kc * 16);
            Ap1[kc] = *(const bf16x8*)(a1 + kc * 16);
        }
    }

    // ---- barrier-free, fully unrolled tap loop ----
    #pragma unroll
    for (int t = 0; t < 27; ++t) {
        // snapshot current phase (SSA copies — free under unroll)
        bf16x8 a[4], b[8];
        #pragma unroll
        for (int kc = 0; kc < 4; ++kc) a[kc] = (t & 1) ? Ap1[kc] : Ap0[kc];
        #pragma unroll
        for (int j = 0; j < 8; ++j)   b[j]  = (t & 1) ? Bp1[j]  : Bp0[j];

        // refill this phase with tap t+2 (arrives ~2 iterations later)
        if (t < 25) {
            const int tn = t + 2;
            const __bf16* wp = Wl + ((size_t)tn << 12);
            const int dx = tn % 3 - 1;
            const int dy = (tn / 3) % 3 - 1;
            const int dz = tn / 9 - 1;
            const __bf16* an = Abase + (dz * HXY + dy * HX + dx) * LDK;
            if (t & 1) {
                #pragma unroll
                for (int kc = 0; kc < 4; ++kc) {
                    Bp1[kc]     = *(const bf16x8*)(wp + kc * 16);
                    Bp1[4 + kc] = *(const bf16x8*)(wp + 2048 + kc * 16);
                    Ap1[kc]     = *(const bf16x8*)(an + kc * 16);
                }
            } else {
                #pragma unroll
                for (int kc = 0; kc < 4; ++kc) {
                    Bp0[kc]     = *(const bf16x8*)(wp + kc * 16);
                    Bp0[4 + kc] = *(const bf16x8*)(wp + 2048 + kc * 16);
                    Ap0[kc]     = *(const bf16x8*)(an + kc * 16);
                }
            }
        }

        #pragma unroll
        for (int kc = 0; kc < 4; ++kc) {
            acc0 = __builtin_amdgcn_mfma_f32_32x32x16_bf16(a[kc], b[kc],     acc0, 0, 0, 0);
            acc1 = __builtin_amdgcn_mfma_f32_32x32x16_bf16(a[kc], b[4 + kc], acc1, 0, 0, 0);
        }
    }

    // ---- epilogue: C/D layout col=lane&31, row=(reg&3)+8*(reg>>2)+4*(lane>>5) ----
    const int col0 = lrow, col1 = 32 + lrow;
    const float bv0 = bias[col0], bv1 = bias[col1];
    #pragma unroll
    for (int r = 0; r < 16; ++r) {
        int mrow = (r & 3) + 8 * (r >> 2) + 4 * halfk;
        int orow = obuf[wave * 32 + mrow];
        if (orow >= 0) {
            out[(size_t)orow * 64 + col0] = acc0[r] + bv0;
            out[(size_t)orow * 64 + col1] = acc1[r] + bv1;
        }
    }
}

extern "C" void kernel_launch(void* const* d_in, const int* in_sizes, int n_in,
                              void* d_out, int out_size, void* d_ws, size_t ws_size,
                              hipStream_t stream) {
    const float* feats = (const float*)d_in[0];
    const float* ipos  = (const float*)d_in[1];
    const float* opos  = (const float*)d_in[2];
    const float* vsp   = (const float*)d_in[3];
    const float* W     = (const float*)d_in[4];
    const float* bias  = (const float*)d_in[5];

    int N = in_sizes[0] / 64;
    int M = out_size / 64;

    // workspace: imap | omap | ikey | okey | Wt   (no clearing required)
    int*    imap = (int*)d_ws;
    int*    omap = imap + NROWS;
    int*    ikey = omap + NROWS;
    int*    okey = ikey + N;
    __bf16* Wt   = (__bf16*)(okey + M);

    int total = N + M + 27*64*64;
    prep_kernel<<<(total + 255) / 256, 256, 0, stream>>>(ipos, N, opos, M, vsp, W,
                                                         imap, ikey, omap, okey, Wt);
    conv_kernel<<<8 * SLAB, 256, 0, stream>>>(feats, Wt, bias, imap, ikey, omap, okey,
                                              (float*)d_out, N, M);
}